// Round 9
// baseline (259.563 us; speedup 1.0000x reference)
//
#include <hip/hip_runtime.h>
#include <hip/hip_bf16.h>
#include <cstdint>
#include <cstddef>

#define BB 256
#define RR 512
#define AA 196
#define VV 10000
#define MATT (BB*AA)   // 50176
#define NT13 13        // 13*16 = 208 cols (Wa2a padded to 208 rows for staging)

typedef float f32x4 __attribute__((ext_vector_type(4)));
typedef __bf16 bf16x8 __attribute__((ext_vector_type(8)));
typedef __bf16 bf16x4 __attribute__((ext_vector_type(4)));

#define MFMA16(a,b,c) __builtin_amdgcn_mfma_f32_16x16x32_bf16(a,b,c,0,0,0)

__device__ __forceinline__ float fast_tanh(float x){
  float ax = fabsf(x);
  float e = __expf(-2.0f*ax);
  float t = __fdividef(1.0f - e, 1.0f + e);
  return x < 0.0f ? -t : t;
}

__device__ __forceinline__ void gload16(const void* gsrc, void* ldsdst){
  __builtin_amdgcn_global_load_lds(
      (const __attribute__((address_space(1))) unsigned int*)gsrc,
      (__attribute__((address_space(3))) unsigned int*)ldsdst,
      16, 0, 0);
}

#define ABAR   asm volatile("s_barrier" ::: "memory")
#define WVM(N) asm volatile("s_waitcnt vmcnt(" #N ")" ::: "memory")

#define CVT8(a, f0, f1) do { \
  a[0]=(__bf16)(f0).x; a[1]=(__bf16)(f0).y; a[2]=(__bf16)(f0).z; a[3]=(__bf16)(f0).w; \
  a[4]=(__bf16)(f1).x; a[5]=(__bf16)(f1).y; a[6]=(__bf16)(f1).z; a[7]=(__bf16)(f1).w; \
} while(0)

// ---------- weight/input prep (vectorized) ----------
__global__ void cvt4_k(const float* __restrict__ src, __bf16* __restrict__ dst, int n4){
  int i = blockIdx.x*256 + threadIdx.x;
  if (i < n4){
    float4 v = ((const float4*)src)[i];
    bf16x4 o;
    o[0]=(__bf16)v.x; o[1]=(__bf16)v.y; o[2]=(__bf16)v.z; o[3]=(__bf16)v.w;
    ((bf16x4*)dst)[i] = o;
  }
}

__global__ void cvt_padrows4_k(const float* __restrict__ src, __bf16* __restrict__ dst, int nvalid){
  int i4 = blockIdx.x*256 + threadIdx.x;
  int row = i4 >> 7, k4 = i4 & 127;
  float4 v = {0,0,0,0};
  if (row < nvalid) v = ((const float4*)(src + (size_t)row*512))[k4];
  bf16x4 o;
  o[0]=(__bf16)v.x; o[1]=(__bf16)v.y; o[2]=(__bf16)v.z; o[3]=(__bf16)v.w;
  ((bf16x4*)(dst))[i4] = o;
}

__global__ void wcat4_k(const float* __restrict__ Wi2h, const float* __restrict__ Wh2h,
                        const float* __restrict__ Wr2a, __bf16* __restrict__ Wcat){
  int k4 = threadIdx.x;     // 0..383
  int n  = blockIdx.x;      // 0..2047
  float4 v;
  if (k4 < 128)      v = ((const float4*)(Wi2h + (size_t)n*512))[k4];
  else if (k4 < 256) v = ((const float4*)(Wh2h + (size_t)n*512))[k4-128];
  else               v = ((const float4*)(Wr2a + (size_t)n*512))[k4-256];
  bf16x4 o;
  o[0]=(__bf16)v.x; o[1]=(__bf16)v.y; o[2]=(__bf16)v.z; o[3]=(__bf16)v.w;
  ((bf16x4*)(Wcat + (size_t)n*1536))[k4] = o;
}

__global__ void build_small_k(const float* __restrict__ ba2a, const float* __restrict__ wd2d,
                              const float* __restrict__ bi2h, const float* __restrict__ bh2h,
                              const float* __restrict__ br2a,
                              float* __restrict__ ba_pad, float* __restrict__ wd_pad,
                              float* __restrict__ bcat){
  int i = blockIdx.x*256 + threadIdx.x;
  if (i < 2048){
    bcat[i] = bi2h[i] + bh2h[i] + br2a[i];
  } else if (i < 2048+256){
    int j = i - 2048; ba_pad[j] = (j < AA) ? ba2a[j] : 0.0f;
  } else if (i < 2048+512){
    int j = i - 2304; wd_pad[j] = (j < AA) ? wd2d[j] : 0.0f;
  }
}

// ---------- pipelined bf16 GEMM (unchanged) ----------
__global__ __launch_bounds__(256,4) void gemm3_k(
    const __bf16* __restrict__ A, const __bf16* __restrict__ Bw,
    const float* __restrict__ bias, float* __restrict__ C,
    int N, int K, int NC)
{
  __shared__ __bf16 AshAll[3*2048];
  __shared__ __bf16 BshAll[3*4096];
  const int t = threadIdx.x;
  const int l = t & 63;
  const int w = t >> 6;
  const int l15 = l & 15;
  const int g  = l >> 4;
  const int rho = l15 & 7;
  const int mrow = blockIdx.y*32;
  const int ncb  = blockIdx.x*64;

  const int arow = t >> 3, aj = t & 7;
  const __bf16* as_ = A + (size_t)(mrow + arow)*K + ((aj ^ (arow&7)) << 3);
  const int aoff = w*512;
  const __bf16* bs0_ = Bw + (size_t)(ncb + arow)*K      + ((aj ^ (arow&7)) << 3);
  const __bf16* bs1_ = Bw + (size_t)(ncb + 32 + arow)*K + ((aj ^ (arow&7)) << 3);
  const int boff0 = w*512;
  const int boff1 = 2048 + w*512;

#define G3_STAGE(B, CH) do { \
    gload16(as_  + (CH)*64, AshAll + (B)*2048 + aoff); \
    gload16(bs0_ + (CH)*64, BshAll + (B)*4096 + boff0); \
    gload16(bs1_ + (CH)*64, BshAll + (B)*4096 + boff1); \
  } while(0)

  f32x4 acc0 = {}, acc1 = {};

#define G3_COMPUTE(B) do { \
    const __bf16* As_ = AshAll + (B)*2048; \
    const __bf16* Bs_ = BshAll + (B)*4096; \
    _Pragma("unroll") \
    for (int s_ = 0; s_ < 2; s_++){ \
      int q_ = (((s_<<2)+g) ^ rho) << 3; \
      bf16x8 a0_ = *(const bf16x8*)(As_ + l15*64 + q_); \
      bf16x8 a1_ = *(const bf16x8*)(As_ + (l15+16)*64 + q_); \
      bf16x8 b_  = *(const bf16x8*)(Bs_ + (w*16+l15)*64 + q_); \
      acc0 = MFMA16(a0_, b_, acc0); \
      acc1 = MFMA16(a1_, b_, acc1); \
    } \
  } while(0)

  G3_STAGE(0,0); G3_STAGE(1,1); G3_STAGE(2,2);
  WVM(6); ABAR;
  int buf = 0;
  for (int c = 0; c < NC; c++){
    G3_COMPUTE(buf);
    if (c + 3 < NC){
      ABAR;
      G3_STAGE(buf, c+3);
      WVM(6); ABAR;
    } else if (c == NC-3){
      WVM(3); ABAR;
    } else if (c == NC-2){
      WVM(0); ABAR;
    }
    buf = (buf == 2) ? 0 : buf + 1;
  }

  int col = ncb + w*16 + l15;
  if (col < N){
    float bv = bias[col];
    #pragma unroll
    for (int r = 0; r < 4; r++){
      C[(size_t)(mrow + g*4 + r)*N + col]      = acc0[r] + bv;
      C[(size_t)(mrow + 16 + g*4 + r)*N + col] = acc1[r] + bv;
    }
  }
#undef G3_STAGE
#undef G3_COMPUTE
}

// ---------- att_score9<V>: ablation-instrumented score kernel ----------
// Block: 64 att rows x 208 cols, K=512 in 16 chunks of 32. 42KB LDS -> 3 blocks/CU.
// A: f32 [64][32] chunk, coalesced gload16, 2-way swizzle. B: bf16 [208][32], 4-way.
// 2 buffers, counted vmcnt(6) (never 0 in steady loop), 6 VMEM/thread/chunk uniform.
// V=0 full | V=1 stage+syncs only | V=2 compute+syncs only | V=3 full minus barriers
template<int V>
__global__ __launch_bounds__(256,3) void att_score9_k(
    const float* __restrict__ att, const __bf16* __restrict__ Wa2a_p,
    const float* __restrict__ ba_pad, const float* __restrict__ wd_pad,
    const float* __restrict__ att_h, float* __restrict__ score)
{
  __shared__ float  Ash[2*2048];    // 2 x [64][32] f32 = 16 KB
  __shared__ __bf16 Bsh[2*6656];    // 2 x [208][32] bf16 = 26 KB
  const int t = threadIdx.x;
  const int l = t & 63;
  const int w = t >> 6;
  const int l15 = l & 15, g = l >> 4;
  const int bid = blockIdx.x;
  const int tile = (bid & 7) * 98 + (bid >> 3);   // 784 = 8*98 bijective XCD swizzle
  const int rowbase = tile * 64;

  // ---- staging descriptors ----
  // A: 512 slots of 16B; slot s -> row=s>>3, sub=s&7; src k-col = (sub ^ (row&7))*4
  const float* aSrc[2]; int aoff[2];
  #pragma unroll
  for (int i = 0; i < 2; i++){
    int slot = i*256 + t;
    int row = slot >> 3, sub = slot & 7;
    aoff[i] = (i*256 + w*64) * 4;                 // wave-uniform float offset
    aSrc[i] = att + (size_t)(rowbase + row)*RR + ((sub ^ (row&7)) << 2);
  }
  // B: 832 slots of 16B; slot s -> row=s>>2, j=s&3; src = (j ^ (row&3))*8
  const __bf16* bSrc[4]; int boff[4];
  #pragma unroll
  for (int i = 0; i < 4; i++){
    int slot = (i < 3) ? (i*256 + t) : (768 + l);   // 4th: all waves dup slots 768..831
    int row = slot >> 2, j = slot & 3;
    boff[i] = ((i < 3) ? (i*256 + w*64) : 768) * 8; // wave-uniform bf16 offset
    bSrc[i] = Wa2a_p + (size_t)row*RR + ((j ^ (row&3)) << 3);
  }

  f32x4 acc[NT13] = {};

#define S9_STAGE(BUF, CH) do { \
    const int kc_ = (CH)*32; \
    gload16(aSrc[0] + kc_, Ash + (BUF)*2048 + aoff[0]); \
    gload16(aSrc[1] + kc_, Ash + (BUF)*2048 + aoff[1]); \
    gload16(bSrc[0] + kc_, Bsh + (BUF)*6656 + boff[0]); \
    gload16(bSrc[1] + kc_, Bsh + (BUF)*6656 + boff[1]); \
    gload16(bSrc[2] + kc_, Bsh + (BUF)*6656 + boff[2]); \
    gload16(bSrc[3] + kc_, Bsh + (BUF)*6656 + boff[3]); \
  } while(0)

  const int arow = w*16 + l15;
  const int ao0 = arow*32 + (((2*g)   ^ (arow&7)) << 2);
  const int ao1 = arow*32 + (((2*g+1) ^ (arow&7)) << 2);

#define S9_COMPUTE(BUF) do { \
    const float*  As_ = Ash + (BUF)*2048; \
    const __bf16* Bs_ = Bsh + (BUF)*6656; \
    float4 fa0 = *(const float4*)(As_ + ao0); \
    float4 fa1 = *(const float4*)(As_ + ao1); \
    bf16x8 a_; CVT8(a_, fa0, fa1); \
    _Pragma("unroll") \
    for (int nt_ = 0; nt_ < NT13; nt_++){ \
      int br_ = nt_*16 + l15; \
      bf16x8 b_ = *(const bf16x8*)(Bs_ + br_*32 + ((g ^ (br_&3)) << 3)); \
      acc[nt_] = MFMA16(a_, b_, acc[nt_]); \
    } \
  } while(0)

  if constexpr (V != 2){ S9_STAGE(0,0); S9_STAGE(1,1); WVM(6); }
  ABAR;
  #pragma unroll
  for (int c = 0; c < 16; c++){
    if constexpr (V != 1) S9_COMPUTE(c & 1);
    if (c < 14){
      if constexpr (V != 3) ABAR;
      if constexpr (V != 2){
        S9_STAGE(c & 1, c + 2);
        WVM(6);
      }
      if constexpr (V != 3) ABAR;
    } else if (c == 14){
      if constexpr (V != 2) WVM(0);
      if constexpr (V != 3) ABAR;
    }
  }

  if constexpr (V == 1){
    // keep staging observable without compute
    score[(size_t)bid*256 + t] = Ash[t] + (float)Bsh[t];
    return;
  }

  // ---- fused epilogue: tanh(acc + ba + att_h) . wd2d, both layers ----
  float wdv[NT13], bav[NT13];
  #pragma unroll
  for (int nt = 0; nt < NT13; nt++){
    int col = nt*16 + l15;
    wdv[nt] = wd_pad[col];
    bav[nt] = ba_pad[col];
  }
  #pragma unroll
  for (int r = 0; r < 4; r++){
    int row = rowbase + w*16 + g*4 + r;
    float ah0 = att_h[row];
    float ah1 = att_h[MATT + row];
    float s0 = 0.0f, s1 = 0.0f;
    #pragma unroll
    for (int nt = 0; nt < NT13; nt++){
      float v = acc[nt][r] + bav[nt];
      s0 += fast_tanh(v + ah0) * wdv[nt];
      s1 += fast_tanh(v + ah1) * wdv[nt];
    }
    #pragma unroll
    for (int o = 1; o < 16; o <<= 1){
      s0 += __shfl_xor(s0, o, 16);
      s1 += __shfl_xor(s1, o, 16);
    }
    if (l15 == 0){
      score[row] = s0;
      score[MATT + row] = s1;
    }
  }
#undef S9_STAGE
#undef S9_COMPUTE
}

// ---------- softmax over 196 positions ----------
__global__ void softmax196_k(const float* __restrict__ score, float* __restrict__ wsm){
  int lb = blockIdx.x;
  int t = threadIdx.x;
  const float* s = score + (size_t)lb*AA;
  float v0 = (t      < AA) ? s[t]       : -3.4e38f;
  float v1 = (t+64   < AA) ? s[t+64]    : -3.4e38f;
  float v2 = (t+128  < AA) ? s[t+128]   : -3.4e38f;
  float v3 = (t+192  < AA) ? s[t+192]   : -3.4e38f;
  float mx = fmaxf(fmaxf(v0,v1), fmaxf(v2,v3));
  #pragma unroll
  for (int o = 1; o < 64; o <<= 1) mx = fmaxf(mx, __shfl_xor(mx, o, 64));
  float e0 = (t      < AA) ? __expf(v0 - mx) : 0.0f;
  float e1 = (t+64   < AA) ? __expf(v1 - mx) : 0.0f;
  float e2 = (t+128  < AA) ? __expf(v2 - mx) : 0.0f;
  float e3 = (t+192  < AA) ? __expf(v3 - mx) : 0.0f;
  float sum = e0+e1+e2+e3;
  #pragma unroll
  for (int o = 1; o < 64; o <<= 1) sum += __shfl_xor(sum, o, 64);
  float inv = 1.0f / sum;
  float* o_ = wsm + (size_t)lb*AA;
  if (t      < AA) o_[t]     = e0*inv;
  if (t+64   < AA) o_[t+64]  = e1*inv;
  if (t+128  < AA) o_[t+128] = e2*inv;
  if (t+192  < AA) o_[t+192] = e3*inv;
}

// ---------- att_res + Xcat fills ----------
__global__ __launch_bounds__(512) void attres3_k(
    const float* __restrict__ att, const float* __restrict__ wsm,
    const float* __restrict__ x, const float* __restrict__ inputs,
    __bf16* __restrict__ Xcat0, __bf16* __restrict__ Xcat1){
  int b = blockIdx.x, t = threadIdx.x;
  __shared__ float w0[208], w1[208];
  __shared__ float4 redv[4][128];
  if (t < AA) w0[t] = wsm[(size_t)b*AA + t];
  int t2 = t - 256;
  if (t2 >= 0 && t2 < AA) w1[t2] = wsm[(size_t)(256+b)*AA + t2];
  Xcat0[(size_t)b*1536 + t]       = (__bf16)x[(size_t)b*512 + t];
  Xcat0[(size_t)b*1536 + 512 + t] = (__bf16)inputs[(size_t)1*131072 + b*512 + t];
  Xcat1[(size_t)b*1536 + 512 + t] = (__bf16)inputs[(size_t)3*131072 + b*512 + t];
  __syncthreads();
  int cg = t & 127, ig = t >> 7;
  const float4* ap = (const float4*)(att + (size_t)b*AA*RR) + cg;
  float4 s0 = {0,0,0,0}, s1 = {0,0,0,0};
  #pragma unroll 4
  for (int i = ig; i < AA; i += 4){
    float4 v = ap[(size_t)i*128];
    float a0 = w0[i], a1 = w1[i];
    s0.x += v.x*a0; s0.y += v.y*a0; s0.z += v.z*a0; s0.w += v.w*a0;
    s1.x += v.x*a1; s1.y += v.y*a1; s1.z += v.z*a1; s1.w += v.w*a1;
  }
  redv[ig][cg] = s0; __syncthreads();
  if (t < 128){
    float4 a = redv[0][t], b4 = redv[1][t], c4 = redv[2][t], d4 = redv[3][t];
    bf16x4 o;
    o[0]=(__bf16)(a.x+b4.x+c4.x+d4.x); o[1]=(__bf16)(a.y+b4.y+c4.y+d4.y);
    o[2]=(__bf16)(a.z+b4.z+c4.z+d4.z); o[3]=(__bf16)(a.w+b4.w+c4.w+d4.w);
    *(bf16x4*)(Xcat0 + (size_t)b*1536 + 1024 + t*4) = o;
  }
  __syncthreads();
  redv[ig][cg] = s1; __syncthreads();
  if (t < 128){
    float4 a = redv[0][t], b4 = redv[1][t], c4 = redv[2][t], d4 = redv[3][t];
    bf16x4 o;
    o[0]=(__bf16)(a.x+b4.x+c4.x+d4.x); o[1]=(__bf16)(a.y+b4.y+c4.y+d4.y);
    o[2]=(__bf16)(a.z+b4.z+c4.z+d4.z); o[3]=(__bf16)(a.w+b4.w+c4.w+d4.w);
    *(bf16x4*)(Xcat1 + (size_t)b*1536 + 1024 + t*4) = o;
  }
}

// ---------- LSTM gates ----------
__global__ void gate_k(const float* __restrict__ sums, const float* __restrict__ prev_c,
                       float* __restrict__ out_c, float* __restrict__ out_h,
                       __bf16* __restrict__ hdst, int hstride){
  int idx = blockIdx.x*256 + threadIdx.x;
  int b = idx >> 9, r = idx & 511;
  const float* s = sums + (size_t)b*2048;
  float ig = 1.0f/(1.0f + __expf(-s[r]));
  float fg = 1.0f/(1.0f + __expf(-s[512+r]));
  float og = 1.0f/(1.0f + __expf(-s[1024+r]));
  float g  = fast_tanh(s[1536+r]);
  float c = fg*prev_c[idx] + ig*g;
  float h = og*fast_tanh(c);
  out_c[idx] = c;
  out_h[idx] = h;
  hdst[(size_t)b*hstride + r] = (__bf16)h;
}

// ---------- log_softmax (float4) ----------
__global__ void logsoftmax4_k(const float* __restrict__ logits, float* __restrict__ out){
  int b = blockIdx.x, t = threadIdx.x;
  __shared__ float red[4], red2[4];
  const float4* p = (const float4*)(logits + (size_t)b*VV);
  float mx = -3.4e38f;
  for (int i = t; i < 2500; i += 256){
    float4 v = p[i];
    mx = fmaxf(mx, fmaxf(fmaxf(v.x,v.y), fmaxf(v.z,v.w)));
  }
  #pragma unroll
  for (int o = 1; o < 64; o <<= 1) mx = fmaxf(mx, __shfl_xor(mx, o, 64));
  if ((t & 63) == 0) red[t >> 6] = mx;
  __syncthreads();
  mx = fmaxf(fmaxf(red[0], red[1]), fmaxf(red[2], red[3]));
  float sum = 0.0f;
  for (int i = t; i < 2500; i += 256){
    float4 v = p[i];
    sum += __expf(v.x-mx) + __expf(v.y-mx) + __expf(v.z-mx) + __expf(v.w-mx);
  }
  #pragma unroll
  for (int o = 1; o < 64; o <<= 1) sum += __shfl_xor(sum, o, 64);
  if ((t & 63) == 0) red2[t >> 6] = sum;
  __syncthreads();
  sum = red2[0] + red2[1] + red2[2] + red2[3];
  float lse = mx + logf(sum);
  float4* q = (float4*)(out + (size_t)b*VV);
  for (int i = t; i < 2500; i += 256){
    float4 v = p[i];
    v.x -= lse; v.y -= lse; v.z -= lse; v.w -= lse;
    q[i] = v;
  }
}

extern "C" void kernel_launch(void* const* d_in, const int* in_sizes, int n_in,
                              void* d_out_, int out_size, void* d_ws, size_t ws_size,
                              hipStream_t stream){
  const float* x     = (const float*)d_in[0];
  const float* att   = (const float*)d_in[1];
  const float* inputs= (const float*)d_in[2];
  const float* Wa2a  = (const float*)d_in[3];
  const float* ba2a  = (const float*)d_in[4];
  const float* Wh2a  = (const float*)d_in[5];
  const float* bh2a  = (const float*)d_in[6];
  const float* wd2d  = (const float*)d_in[7];
  const float* Wi2h  = (const float*)d_in[9];
  const float* bi2h  = (const float*)d_in[10];
  const float* Wh2h  = (const float*)d_in[11];
  const float* bh2h  = (const float*)d_in[12];
  const float* Wr2a  = (const float*)d_in[13];
  const float* br2a  = (const float*)d_in[14];
  const float* Wproj = (const float*)d_in[15];
  const float* bproj = (const float*)d_in[16];
  float* d_out = (float*)d_out_;

  char* wsp = (char*)d_ws;
  auto alloc = [&](size_t bytes)->char*{
    char* p = wsp;
    wsp += (bytes + 255) & ~(size_t)255;
    return p;
  };
  __bf16* Wa2a_p   = (__bf16*)alloc((size_t)256*RR*2);     // rows >=196 zero
  __bf16* Wh2a_pad = (__bf16*)alloc((size_t)256*RR*2);
  __bf16* Wcat_bf  = (__bf16*)alloc((size_t)2048*1536*2);
  __bf16* Wproj_bf = (__bf16*)alloc((size_t)10048*RR*2);
  __bf16* inp_bf   = (__bf16*)alloc((size_t)512*RR*2);
  float* ba_pad = (float*)alloc(256*4);
  float* wd_pad = (float*)alloc(256*4);
  float* bcat   = (float*)alloc(2048*4);
  float* att_h  = (float*)alloc((size_t)2*MATT*4);
  float* score  = (float*)alloc((size_t)2*MATT*4);
  float* wsm    = (float*)alloc((size_t)2*MATT*4);
  __bf16* Xcat0 = (__bf16*)alloc((size_t)BB*1536*2);
  __bf16* Xcat1 = (__bf16*)alloc((size_t)BB*1536*2);
  float* sums   = (float*)alloc((size_t)BB*2048*4);
  __bf16* h1_bf = (__bf16*)alloc((size_t)BB*RR*2);
  float* logits = (float*)alloc((size_t)BB*VV*4);
  float* ablscr = (float*)alloc((size_t)784*256*4);        // ablation scratch

  // prep
  cvt_padrows4_k<<<(256*128)/256, 256, 0, stream>>>(Wa2a, Wa2a_p, AA);
  cvt_padrows4_k<<<(256*128)/256, 256, 0, stream>>>(Wh2a, Wh2a_pad, AA);
  cvt_padrows4_k<<<(10048*128)/256, 256, 0, stream>>>(Wproj, Wproj_bf, VV);
  cvt4_k<<<(131072/4)/256, 256, 0, stream>>>(inputs + 1*131072, inp_bf, 131072/4);
  cvt4_k<<<(131072/4)/256, 256, 0, stream>>>(inputs + 3*131072, inp_bf + 131072, 131072/4);
  wcat4_k<<<2048, 384, 0, stream>>>(Wi2h, Wh2h, Wr2a, Wcat_bf);
  build_small_k<<<10, 256, 0, stream>>>(ba2a, wd2d, bi2h, bh2h, br2a, ba_pad, wd_pad, bcat);

  // att_h for both layers
  gemm3_k<<<dim3(4,16), 256, 0, stream>>>(inp_bf, Wh2a_pad, bh2a, att_h, AA, 512, 8);

  // ---- ablation probes (scratch) + real score ----
  att_score9_k<1><<<784, 256, 0, stream>>>(att, Wa2a_p, ba_pad, wd_pad, att_h, ablscr);
  att_score9_k<2><<<784, 256, 0, stream>>>(att, Wa2a_p, ba_pad, wd_pad, att_h, ablscr);
  att_score9_k<3><<<784, 256, 0, stream>>>(att, Wa2a_p, ba_pad, wd_pad, att_h, ablscr);
  att_score9_k<0><<<784, 256, 0, stream>>>(att, Wa2a_p, ba_pad, wd_pad, att_h, score);

  softmax196_k<<<512, 64, 0, stream>>>(score, wsm);
  attres3_k<<<256, 512, 0, stream>>>(att, wsm, x, inputs, Xcat0, Xcat1);

  // layer 0
  gemm3_k<<<dim3(32,8), 256, 0, stream>>>(Xcat0, Wcat_bf, bcat, sums, 2048, 1536, 24);
  gate_k<<<512, 256, 0, stream>>>(sums, inputs, d_out, d_out + 131072, Xcat1, 1536);
  // layer 1
  gemm3_k<<<dim3(32,8), 256, 0, stream>>>(Xcat1, Wcat_bf, bcat, sums, 2048, 1536, 24);
  gate_k<<<512, 256, 0, stream>>>(sums, inputs + 2*131072, d_out + 2*131072, d_out + 3*131072, h1_bf, 512);

  // projection + log_softmax
  gemm3_k<<<dim3(157,8), 256, 0, stream>>>(h1_bf, Wproj_bf, bproj, logits, VV, 512, 8);
  logsoftmax4_k<<<256, 256, 0, stream>>>(logits, d_out + 4*131072);
}

// Round 10
// 139.375 us; speedup vs baseline: 1.8623x; 1.8623x over previous
//
#include <hip/hip_runtime.h>
#include <hip/hip_bf16.h>
#include <cstdint>
#include <cstddef>

#define BB 256
#define RR 512
#define AA 196
#define VV 10000
#define MATT (BB*AA)   // 50176
#define NT13 13        // 13*16 = 208 cols

typedef float f32x4 __attribute__((ext_vector_type(4)));
typedef __bf16 bf16x8 __attribute__((ext_vector_type(8)));
typedef __bf16 bf16x4 __attribute__((ext_vector_type(4)));

#define MFMA16(a,b,c) __builtin_amdgcn_mfma_f32_16x16x32_bf16(a,b,c,0,0,0)

__device__ __forceinline__ float fast_tanh(float x){
  float ax = fabsf(x);
  float e = __expf(-2.0f*ax);
  float t = __fdividef(1.0f - e, 1.0f + e);
  return x < 0.0f ? -t : t;
}

__device__ __forceinline__ void gload16(const void* gsrc, void* ldsdst){
  __builtin_amdgcn_global_load_lds(
      (const __attribute__((address_space(1))) unsigned int*)gsrc,
      (__attribute__((address_space(3))) unsigned int*)ldsdst,
      16, 0, 0);
}

#define ABAR   asm volatile("s_barrier" ::: "memory")
#define WVM(N) asm volatile("s_waitcnt vmcnt(" #N ")" ::: "memory")

#define CVT8(a, f0, f1) do { \
  a[0]=(__bf16)(f0).x; a[1]=(__bf16)(f0).y; a[2]=(__bf16)(f0).z; a[3]=(__bf16)(f0).w; \
  a[4]=(__bf16)(f1).x; a[5]=(__bf16)(f1).y; a[6]=(__bf16)(f1).z; a[7]=(__bf16)(f1).w; \
} while(0)

// ---------- single fused prep kernel: all weight/input conversions ----------
// Item space (one item per thread, grid sized exactly):
//  [0, 32768)                      Wa2a_p   quad (row<196 else 0)
//  [32768, 65536)                  Wh2a_pad quad
//  [65536, 1351680)                Wproj_bf quad (row<10000 else 0)   (1286144 items)
//  [1351680, 1417216)              inp_bf   quad (first 32768 = inputs[1], next = inputs[3])
//  [1417216, 2203648)              Wcat_bf  quad (n = q/384, k4 = q%384)
//  [2203648, 2206208)              scalars: bcat(2048), ba_pad(256), wd_pad(256)
__global__ void prep_all_k(
    const float* __restrict__ Wa2a, const float* __restrict__ Wh2a,
    const float* __restrict__ Wproj, const float* __restrict__ inputs,
    const float* __restrict__ Wi2h, const float* __restrict__ Wh2h,
    const float* __restrict__ Wr2a, const float* __restrict__ ba2a,
    const float* __restrict__ wd2d, const float* __restrict__ bi2h,
    const float* __restrict__ bh2h, const float* __restrict__ br2a,
    __bf16* __restrict__ Wa2a_p, __bf16* __restrict__ Wh2a_pad,
    __bf16* __restrict__ Wproj_bf, __bf16* __restrict__ inp_bf,
    __bf16* __restrict__ Wcat_bf,
    float* __restrict__ ba_pad, float* __restrict__ wd_pad, float* __restrict__ bcat)
{
  size_t q = (size_t)blockIdx.x*256 + threadIdx.x;
  float4 v = {0,0,0,0};
  __bf16* dst = nullptr;
  size_t dq = 0;
  if (q < 32768){
    int row = q >> 7, k4 = q & 127;
    if (row < AA) v = ((const float4*)(Wa2a + (size_t)row*512))[k4];
    dst = Wa2a_p; dq = q;
  } else if (q < 65536){
    size_t ql = q - 32768;
    int row = ql >> 7, k4 = ql & 127;
    if (row < AA) v = ((const float4*)(Wh2a + (size_t)row*512))[k4];
    dst = Wh2a_pad; dq = ql;
  } else if (q < 1351680){
    size_t ql = q - 65536;
    int row = ql >> 7, k4 = ql & 127;
    if (row < VV) v = ((const float4*)(Wproj + (size_t)row*512))[k4];
    dst = Wproj_bf; dq = ql;
  } else if (q < 1417216){
    size_t ql = q - 1351680;
    const float* src = (ql < 32768) ? (inputs + 1*131072) : (inputs + 3*131072 - 131072);
    v = ((const float4*)src)[ql];   // for ql>=32768: src+131072 floats = inputs3 base
    dst = inp_bf; dq = ql;
  } else if (q < 2203648){
    size_t ql = q - 1417216;
    int n = ql / 384, k4 = ql - (size_t)n*384;
    if (k4 < 128)      v = ((const float4*)(Wi2h + (size_t)n*512))[k4];
    else if (k4 < 256) v = ((const float4*)(Wh2h + (size_t)n*512))[k4-128];
    else               v = ((const float4*)(Wr2a + (size_t)n*512))[k4-256];
    dst = Wcat_bf; dq = (size_t)n*384 + k4;
  } else {
    size_t i = q - 2203648;
    if (i < 2048)       bcat[i] = bi2h[i] + bh2h[i] + br2a[i];
    else if (i < 2304){ int j = i - 2048; ba_pad[j] = (j < AA) ? ba2a[j] : 0.0f; }
    else              { int j = i - 2304; wd_pad[j] = (j < AA) ? wd2d[j] : 0.0f; }
    return;
  }
  bf16x4 o;
  o[0]=(__bf16)v.x; o[1]=(__bf16)v.y; o[2]=(__bf16)v.z; o[3]=(__bf16)v.w;
  ((bf16x4*)dst)[dq] = o;
}

// ---------- pipelined bf16 GEMM: C[m][n] = sum_k A[m][k]*W[n][k] + bias[n] ----------
__global__ __launch_bounds__(256,4) void gemm3_k(
    const __bf16* __restrict__ A, const __bf16* __restrict__ Bw,
    const float* __restrict__ bias, float* __restrict__ C,
    int N, int K, int NC)
{
  __shared__ __bf16 AshAll[3*2048];
  __shared__ __bf16 BshAll[3*4096];
  const int t = threadIdx.x;
  const int l = t & 63;
  const int w = t >> 6;
  const int l15 = l & 15;
  const int g  = l >> 4;
  const int rho = l15 & 7;
  const int mrow = blockIdx.y*32;
  const int ncb  = blockIdx.x*64;

  const int arow = t >> 3, aj = t & 7;
  const __bf16* as_ = A + (size_t)(mrow + arow)*K + ((aj ^ (arow&7)) << 3);
  const int aoff = w*512;
  const __bf16* bs0_ = Bw + (size_t)(ncb + arow)*K      + ((aj ^ (arow&7)) << 3);
  const __bf16* bs1_ = Bw + (size_t)(ncb + 32 + arow)*K + ((aj ^ (arow&7)) << 3);
  const int boff0 = w*512;
  const int boff1 = 2048 + w*512;

#define G3_STAGE(B, CH) do { \
    gload16(as_  + (CH)*64, AshAll + (B)*2048 + aoff); \
    gload16(bs0_ + (CH)*64, BshAll + (B)*4096 + boff0); \
    gload16(bs1_ + (CH)*64, BshAll + (B)*4096 + boff1); \
  } while(0)

  f32x4 acc0 = {}, acc1 = {};

#define G3_COMPUTE(B) do { \
    const __bf16* As_ = AshAll + (B)*2048; \
    const __bf16* Bs_ = BshAll + (B)*4096; \
    _Pragma("unroll") \
    for (int s_ = 0; s_ < 2; s_++){ \
      int q_ = (((s_<<2)+g) ^ rho) << 3; \
      bf16x8 a0_ = *(const bf16x8*)(As_ + l15*64 + q_); \
      bf16x8 a1_ = *(const bf16x8*)(As_ + (l15+16)*64 + q_); \
      bf16x8 b_  = *(const bf16x8*)(Bs_ + (w*16+l15)*64 + q_); \
      acc0 = MFMA16(a0_, b_, acc0); \
      acc1 = MFMA16(a1_, b_, acc1); \
    } \
  } while(0)

  G3_STAGE(0,0); G3_STAGE(1,1); G3_STAGE(2,2);
  WVM(6); ABAR;
  int buf = 0;
  for (int c = 0; c < NC; c++){
    G3_COMPUTE(buf);
    if (c + 3 < NC){
      ABAR;
      G3_STAGE(buf, c+3);
      WVM(6); ABAR;
    } else if (c == NC-3){
      WVM(3); ABAR;
    } else if (c == NC-2){
      WVM(0); ABAR;
    }
    buf = (buf == 2) ? 0 : buf + 1;
  }

  int col = ncb + w*16 + l15;
  if (col < N){
    float bv = bias[col];
    #pragma unroll
    for (int r = 0; r < 4; r++){
      C[(size_t)(mrow + g*4 + r)*N + col]      = acc0[r] + bv;
      C[(size_t)(mrow + 16 + g*4 + r)*N + col] = acc1[r] + bv;
    }
  }
#undef G3_STAGE
#undef G3_COMPUTE
}

// ---------- att_score9 (round-9 V0): 2-buffer counted-vmcnt, 3 blocks/CU ----------
__global__ __launch_bounds__(256,3) void att_score9_k(
    const float* __restrict__ att, const __bf16* __restrict__ Wa2a_p,
    const float* __restrict__ ba_pad, const float* __restrict__ wd_pad,
    const float* __restrict__ att_h, float* __restrict__ score)
{
  __shared__ float  Ash[2*2048];    // 2 x [64][32] f32
  __shared__ __bf16 Bsh[2*6656];    // 2 x [208][32] bf16
  const int t = threadIdx.x;
  const int l = t & 63;
  const int w = t >> 6;
  const int l15 = l & 15, g = l >> 4;
  const int bid = blockIdx.x;
  const int tile = (bid & 7) * 98 + (bid >> 3);
  const int rowbase = tile * 64;

  const float* aSrc[2]; int aoff[2];
  #pragma unroll
  for (int i = 0; i < 2; i++){
    int slot = i*256 + t;
    int row = slot >> 3, sub = slot & 7;
    aoff[i] = (i*256 + w*64) * 4;
    aSrc[i] = att + (size_t)(rowbase + row)*RR + ((sub ^ (row&7)) << 2);
  }
  const __bf16* bSrc[4]; int boff[4];
  #pragma unroll
  for (int i = 0; i < 4; i++){
    int slot = (i < 3) ? (i*256 + t) : (768 + l);
    int row = slot >> 2, j = slot & 3;
    boff[i] = ((i < 3) ? (i*256 + w*64) : 768) * 8;
    bSrc[i] = Wa2a_p + (size_t)row*RR + ((j ^ (row&3)) << 3);
  }

  f32x4 acc[NT13] = {};

#define S9_STAGE(BUF, CH) do { \
    const int kc_ = (CH)*32; \
    gload16(aSrc[0] + kc_, Ash + (BUF)*2048 + aoff[0]); \
    gload16(aSrc[1] + kc_, Ash + (BUF)*2048 + aoff[1]); \
    gload16(bSrc[0] + kc_, Bsh + (BUF)*6656 + boff[0]); \
    gload16(bSrc[1] + kc_, Bsh + (BUF)*6656 + boff[1]); \
    gload16(bSrc[2] + kc_, Bsh + (BUF)*6656 + boff[2]); \
    gload16(bSrc[3] + kc_, Bsh + (BUF)*6656 + boff[3]); \
  } while(0)

  const int arow = w*16 + l15;
  const int ao0 = arow*32 + (((2*g)   ^ (arow&7)) << 2);
  const int ao1 = arow*32 + (((2*g+1) ^ (arow&7)) << 2);

#define S9_COMPUTE(BUF) do { \
    const float*  As_ = Ash + (BUF)*2048; \
    const __bf16* Bs_ = Bsh + (BUF)*6656; \
    float4 fa0 = *(const float4*)(As_ + ao0); \
    float4 fa1 = *(const float4*)(As_ + ao1); \
    bf16x8 a_; CVT8(a_, fa0, fa1); \
    _Pragma("unroll") \
    for (int nt_ = 0; nt_ < NT13; nt_++){ \
      int br_ = nt_*16 + l15; \
      bf16x8 b_ = *(const bf16x8*)(Bs_ + br_*32 + ((g ^ (br_&3)) << 3)); \
      acc[nt_] = MFMA16(a_, b_, acc[nt_]); \
    } \
  } while(0)

  S9_STAGE(0,0); S9_STAGE(1,1); WVM(6);
  ABAR;
  #pragma unroll
  for (int c = 0; c < 16; c++){
    S9_COMPUTE(c & 1);
    if (c < 14){
      ABAR;
      S9_STAGE(c & 1, c + 2);
      WVM(6);
      ABAR;
    } else if (c == 14){
      WVM(0);
      ABAR;
    }
  }

  float wdv[NT13], bav[NT13];
  #pragma unroll
  for (int nt = 0; nt < NT13; nt++){
    int col = nt*16 + l15;
    wdv[nt] = wd_pad[col];
    bav[nt] = ba_pad[col];
  }
  #pragma unroll
  for (int r = 0; r < 4; r++){
    int row = rowbase + w*16 + g*4 + r;
    float ah0 = att_h[row];
    float ah1 = att_h[MATT + row];
    float s0 = 0.0f, s1 = 0.0f;
    #pragma unroll
    for (int nt = 0; nt < NT13; nt++){
      float v = acc[nt][r] + bav[nt];
      s0 += fast_tanh(v + ah0) * wdv[nt];
      s1 += fast_tanh(v + ah1) * wdv[nt];
    }
    #pragma unroll
    for (int o = 1; o < 16; o <<= 1){
      s0 += __shfl_xor(s0, o, 16);
      s1 += __shfl_xor(s1, o, 16);
    }
    if (l15 == 0){
      score[row] = s0;
      score[MATT + row] = s1;
    }
  }
#undef S9_STAGE
#undef S9_COMPUTE
}

// ---------- fused softmax + att_res + Xcat fills (per-b block) ----------
__global__ __launch_bounds__(512) void attres_sm_k(
    const float* __restrict__ att, const float* __restrict__ score,
    const float* __restrict__ x, const float* __restrict__ inputs,
    __bf16* __restrict__ Xcat0, __bf16* __restrict__ Xcat1)
{
  int b = blockIdx.x, t = threadIdx.x;   // 512 threads
  __shared__ float wv[2][256];
  __shared__ float4 redv[4][128];
  const int w = t >> 6, l = t & 63;

  // softmax for both layers: wave 0 -> layer 0, wave 1 -> layer 1
  if (w < 2){
    const float* s = score + (size_t)w*MATT + (size_t)b*AA;
    float v[4], e[4];
    #pragma unroll
    for (int j = 0; j < 4; j++){
      int i = l + j*64;
      v[j] = (i < AA) ? s[i] : -3.4e38f;
    }
    float mx = fmaxf(fmaxf(v[0],v[1]), fmaxf(v[2],v[3]));
    #pragma unroll
    for (int o = 1; o < 64; o <<= 1) mx = fmaxf(mx, __shfl_xor(mx, o, 64));
    float sum = 0.0f;
    #pragma unroll
    for (int j = 0; j < 4; j++){
      int i = l + j*64;
      e[j] = (i < AA) ? __expf(v[j] - mx) : 0.0f;
      sum += e[j];
    }
    #pragma unroll
    for (int o = 1; o < 64; o <<= 1) sum += __shfl_xor(sum, o, 64);
    float inv = 1.0f / sum;
    #pragma unroll
    for (int j = 0; j < 4; j++) wv[w][l + j*64] = e[j]*inv;
  }
  // Xcat direct fills (independent of softmax)
  Xcat0[(size_t)b*1536 + t]       = (__bf16)x[(size_t)b*512 + t];
  Xcat0[(size_t)b*1536 + 512 + t] = (__bf16)inputs[(size_t)1*131072 + b*512 + t];
  Xcat1[(size_t)b*1536 + 512 + t] = (__bf16)inputs[(size_t)3*131072 + b*512 + t];
  __syncthreads();

  // att_res: sum_i wv[l][i] * att[b,i,:]
  int cg = t & 127, ig = t >> 7;
  const float4* ap = (const float4*)(att + (size_t)b*AA*RR) + cg;
  float4 s0 = {0,0,0,0}, s1 = {0,0,0,0};
  #pragma unroll 4
  for (int i = ig; i < AA; i += 4){
    float4 v = ap[(size_t)i*128];
    float a0 = wv[0][i], a1 = wv[1][i];
    s0.x += v.x*a0; s0.y += v.y*a0; s0.z += v.z*a0; s0.w += v.w*a0;
    s1.x += v.x*a1; s1.y += v.y*a1; s1.z += v.z*a1; s1.w += v.w*a1;
  }
  redv[ig][cg] = s0; __syncthreads();
  if (t < 128){
    float4 a = redv[0][t], b4 = redv[1][t], c4 = redv[2][t], d4 = redv[3][t];
    bf16x4 o;
    o[0]=(__bf16)(a.x+b4.x+c4.x+d4.x); o[1]=(__bf16)(a.y+b4.y+c4.y+d4.y);
    o[2]=(__bf16)(a.z+b4.z+c4.z+d4.z); o[3]=(__bf16)(a.w+b4.w+c4.w+d4.w);
    *(bf16x4*)(Xcat0 + (size_t)b*1536 + 1024 + t*4) = o;
  }
  __syncthreads();
  redv[ig][cg] = s1; __syncthreads();
  if (t < 128){
    float4 a = redv[0][t], b4 = redv[1][t], c4 = redv[2][t], d4 = redv[3][t];
    bf16x4 o;
    o[0]=(__bf16)(a.x+b4.x+c4.x+d4.x); o[1]=(__bf16)(a.y+b4.y+c4.y+d4.y);
    o[2]=(__bf16)(a.z+b4.z+c4.z+d4.z); o[3]=(__bf16)(a.w+b4.w+c4.w+d4.w);
    *(bf16x4*)(Xcat1 + (size_t)b*1536 + 1024 + t*4) = o;
  }
}

// ---------- LSTM gates ----------
__global__ void gate_k(const float* __restrict__ sums, const float* __restrict__ prev_c,
                       float* __restrict__ out_c, float* __restrict__ out_h,
                       __bf16* __restrict__ hdst, int hstride){
  int idx = blockIdx.x*256 + threadIdx.x;
  int b = idx >> 9, r = idx & 511;
  const float* s = sums + (size_t)b*2048;
  float ig = 1.0f/(1.0f + __expf(-s[r]));
  float fg = 1.0f/(1.0f + __expf(-s[512+r]));
  float og = 1.0f/(1.0f + __expf(-s[1024+r]));
  float g  = fast_tanh(s[1536+r]);
  float c = fg*prev_c[idx] + ig*g;
  float h = og*fast_tanh(c);
  out_c[idx] = c;
  out_h[idx] = h;
  hdst[(size_t)b*hstride + r] = (__bf16)h;
}

// ---------- log_softmax (float4) ----------
__global__ void logsoftmax4_k(const float* __restrict__ logits, float* __restrict__ out){
  int b = blockIdx.x, t = threadIdx.x;
  __shared__ float red[4], red2[4];
  const float4* p = (const float4*)(logits + (size_t)b*VV);
  float mx = -3.4e38f;
  for (int i = t; i < 2500; i += 256){
    float4 v = p[i];
    mx = fmaxf(mx, fmaxf(fmaxf(v.x,v.y), fmaxf(v.z,v.w)));
  }
  #pragma unroll
  for (int o = 1; o < 64; o <<= 1) mx = fmaxf(mx, __shfl_xor(mx, o, 64));
  if ((t & 63) == 0) red[t >> 6] = mx;
  __syncthreads();
  mx = fmaxf(fmaxf(red[0], red[1]), fmaxf(red[2], red[3]));
  float sum = 0.0f;
  for (int i = t; i < 2500; i += 256){
    float4 v = p[i];
    sum += __expf(v.x-mx) + __expf(v.y-mx) + __expf(v.z-mx) + __expf(v.w-mx);
  }
  #pragma unroll
  for (int o = 1; o < 64; o <<= 1) sum += __shfl_xor(sum, o, 64);
  if ((t & 63) == 0) red2[t >> 6] = sum;
  __syncthreads();
  sum = red2[0] + red2[1] + red2[2] + red2[3];
  float lse = mx + logf(sum);
  float4* q = (float4*)(out + (size_t)b*VV);
  for (int i = t; i < 2500; i += 256){
    float4 v = p[i];
    v.x -= lse; v.y -= lse; v.z -= lse; v.w -= lse;
    q[i] = v;
  }
}

extern "C" void kernel_launch(void* const* d_in, const int* in_sizes, int n_in,
                              void* d_out_, int out_size, void* d_ws, size_t ws_size,
                              hipStream_t stream){
  const float* x     = (const float*)d_in[0];
  const float* att   = (const float*)d_in[1];
  const float* inputs= (const float*)d_in[2];
  const float* Wa2a  = (const float*)d_in[3];
  const float* ba2a  = (const float*)d_in[4];
  const float* Wh2a  = (const float*)d_in[5];
  const float* bh2a  = (const float*)d_in[6];
  const float* wd2d  = (const float*)d_in[7];
  // d_in[8] = bd2d : uniform pre-softmax scalar -> softmax-invariant, unused
  const float* Wi2h  = (const float*)d_in[9];
  const float* bi2h  = (const float*)d_in[10];
  const float* Wh2h  = (const float*)d_in[11];
  const float* bh2h  = (const float*)d_in[12];
  const float* Wr2a  = (const float*)d_in[13];
  const float* br2a  = (const float*)d_in[14];
  const float* Wproj = (const float*)d_in[15];
  const float* bproj = (const float*)d_in[16];
  float* d_out = (float*)d_out_;

  char* wsp = (char*)d_ws;
  auto alloc = [&](size_t bytes)->char*{
    char* p = wsp;
    wsp += (bytes + 255) & ~(size_t)255;
    return p;
  };
  __bf16* Wa2a_p   = (__bf16*)alloc((size_t)256*RR*2);
  __bf16* Wh2a_pad = (__bf16*)alloc((size_t)256*RR*2);
  __bf16* Wcat_bf  = (__bf16*)alloc((size_t)2048*1536*2);
  __bf16* Wproj_bf = (__bf16*)alloc((size_t)10048*RR*2);
  __bf16* inp_bf   = (__bf16*)alloc((size_t)512*RR*2);
  float* ba_pad = (float*)alloc(256*4);
  float* wd_pad = (float*)alloc(256*4);
  float* bcat   = (float*)alloc(2048*4);
  float* att_h  = (float*)alloc((size_t)2*MATT*4);
  float* score  = (float*)alloc((size_t)2*MATT*4);
  __bf16* Xcat0 = (__bf16*)alloc((size_t)BB*1536*2);
  __bf16* Xcat1 = (__bf16*)alloc((size_t)BB*1536*2);
  float* sums   = (float*)alloc((size_t)BB*2048*4);
  __bf16* h1_bf = (__bf16*)alloc((size_t)BB*RR*2);
  float* logits = (float*)alloc((size_t)BB*VV*4);

  // one fused prep launch (2,206,208 items / 256 = 8618 blocks)
  prep_all_k<<<8618, 256, 0, stream>>>(
      Wa2a, Wh2a, Wproj, inputs, Wi2h, Wh2h, Wr2a, ba2a, wd2d, bi2h, bh2h, br2a,
      Wa2a_p, Wh2a_pad, Wproj_bf, inp_bf, Wcat_bf, ba_pad, wd_pad, bcat);

  // att_h for both layers (fixed inputs): [512 rows][196]
  gemm3_k<<<dim3(4,16), 256, 0, stream>>>(inp_bf, Wh2a_pad, bh2a, att_h, AA, 512, 8);

  // attention
  att_score9_k<<<784, 256, 0, stream>>>(att, Wa2a_p, ba_pad, wd_pad, att_h, score);
  attres_sm_k<<<256, 512, 0, stream>>>(att, score, x, inputs, Xcat0, Xcat1);

  // layer 0
  gemm3_k<<<dim3(32,8), 256, 0, stream>>>(Xcat0, Wcat_bf, bcat, sums, 2048, 1536, 24);
  gate_k<<<512, 256, 0, stream>>>(sums, inputs, d_out, d_out + 131072, Xcat1, 1536);
  // layer 1
  gemm3_k<<<dim3(32,8), 256, 0, stream>>>(Xcat1, Wcat_bf, bcat, sums, 2048, 1536, 24);
  gate_k<<<512, 256, 0, stream>>>(sums, inputs + 2*131072, d_out + 2*131072, d_out + 3*131072, h1_bf, 512);

  // projection + log_softmax
  gemm3_k<<<dim3(157,8), 256, 0, stream>>>(h1_bf, Wproj_bf, bproj, logits, VV, 512, 8);
  logsoftmax4_k<<<256, 256, 0, stream>>>(logits, d_out + 4*131072);
}